// Round 1
// baseline (509.115 us; speedup 1.0000x reference)
//
#include <hip/hip_runtime.h>

#define NB 256   // batch
#define NT 512   // time steps
#define ND 128   // input dim
#define NU 128   // hidden dim
#define NC 64    // classes

// fast tanh: 1 - 2/(e^{2x}+1); correct limits for |x| large, ~1e-6 abs error
__device__ __forceinline__ float fast_tanh(float x) {
  float e = __expf(2.0f * x);
  return 1.0f - 2.0f / (e + 1.0f);
}

// LDS-only barrier: drains LDS ops, does NOT drain vmcnt (avoids the
// compiler's full vmem drain before s_barrier which would stall the
// x-prefetch pipeline every step).
__device__ __forceinline__ void wg_barrier() {
  asm volatile("s_waitcnt lgkmcnt(0)\n\ts_barrier" ::: "memory");
}

// Block: 576 threads = 9 waves.
//   tid <  512 : compute. layout A: j = tid&127, kg = tid>>7  (4 k-groups of 32)
//                          layout B: c = tid&63,  kg2 = tid>>6 (8 k-groups of 16)
//   tid >= 512 : wave 8 = x staging (32 lanes x float4 = one 512B row per step)
__global__ __launch_bounds__(576) void rnn_fused(
    const float* __restrict__ x,    // (B,T,D)
    const float* __restrict__ W1,   // (D,U)
    const float* __restrict__ b1v,  // (U)
    const float* __restrict__ W2,   // (U,U)
    const float* __restrict__ b2v,  // (U)
    const float* __restrict__ Wc,   // (U,C)
    const float* __restrict__ bcv,  // (C)
    float* __restrict__ out)        // (B,T,C)
{
  __shared__ float  xring[8][ND];     // ring of x rows
  __shared__ float  vst[NU];          // state y_{t-1}
  __shared__ float2 partHR[4][NU];    // {h,r} partials per k-group
  __shared__ float  partC[8][NC];     // classifier partials

  const int tid = (int)threadIdx.x;
  const int b   = (int)blockIdx.x;
  const float* xrow = x + (size_t)b * NT * ND;
  const float4* xr4 = (const float4*)xrow;

  const int j   = tid & (NU - 1);
  const int kg  = (tid >> 7) & 3;
  const int cc  = tid & (NC - 1);
  const int kg2 = (tid >> 6) & 7;
  const int lt  = tid - 512;  // staging lane (wave 8)

  float w1r[32], w2r[32], wcr[16];
  float bias1 = 0.f, bias2 = 0.f, biasc = 0.f;

  if (tid < 512) {
#pragma unroll
    for (int i = 0; i < 32; ++i) {
      w1r[i] = W1[(kg * 32 + i) * NU + j];
      w2r[i] = W2[(kg * 32 + i) * NU + j];
    }
#pragma unroll
    for (int i = 0; i < 16; ++i) wcr[i] = Wc[(kg2 * 16 + i) * NC + cc];
    bias1 = b1v[j];
    bias2 = b2v[j];
    biasc = bcv[cc];
    if (tid < NU) vst[tid] = 0.f;
  }

  // x staging prologue: rows 0,1 -> LDS now; rows 2..5 -> in-flight regs
  float4 xq0 = make_float4(0.f, 0.f, 0.f, 0.f);
  float4 xq1 = xq0, xq2 = xq0, xq3 = xq0;
  if (lt >= 0 && lt < 32) {
    float4 r0 = xr4[0 * 32 + lt];
    float4 r1 = xr4[1 * 32 + lt];
    ((float4*)xring[0])[lt] = r0;
    ((float4*)xring[1])[lt] = r1;
    xq0 = xr4[2 * 32 + lt];
    xq1 = xr4[3 * 32 + lt];
    xq2 = xr4[4 * 32 + lt];
    xq3 = xr4[5 * 32 + lt];
  }
  __syncthreads();  // one full barrier pre-loop is fine

// One recurrence step. t_ must satisfy (t_ & 3) == phase of XQ_.
// Epoch 1 (pre barrier 1): compute partials (reads xring[t&7], vst);
//   wave8 writes ring[(t+2)&7] from reg loaded 4 steps ago, issues load t+6.
// Epoch 2 (between barriers): finishers update vst (tid<128) and store
//   out[t-1] (tid in [128,192)).
#define STEP(T_, XQ_)                                                          \
  {                                                                            \
    const int t_ = (T_);                                                       \
    if (tid < 512) {                                                           \
      float accH = 0.f, accR = 0.f, accC = 0.f;                                \
      const float4* xb4 = (const float4*)(&xring[t_ & 7][kg * 32]);            \
      const float4* vb4 = (const float4*)(&vst[kg * 32]);                      \
      _Pragma("unroll") for (int i = 0; i < 8; ++i) {                          \
        float4 xv = xb4[i];                                                    \
        float4 vv = vb4[i];                                                    \
        accH = fmaf(xv.x, w1r[4 * i + 0], accH);                               \
        accH = fmaf(xv.y, w1r[4 * i + 1], accH);                               \
        accH = fmaf(xv.z, w1r[4 * i + 2], accH);                               \
        accH = fmaf(xv.w, w1r[4 * i + 3], accH);                               \
        accR = fmaf(vv.x, w2r[4 * i + 0], accR);                               \
        accR = fmaf(vv.y, w2r[4 * i + 1], accR);                               \
        accR = fmaf(vv.z, w2r[4 * i + 2], accR);                               \
        accR = fmaf(vv.w, w2r[4 * i + 3], accR);                               \
      }                                                                        \
      const float4* vc4 = (const float4*)(&vst[kg2 * 16]);                     \
      _Pragma("unroll") for (int i = 0; i < 4; ++i) {                          \
        float4 vv = vc4[i];                                                    \
        accC = fmaf(vv.x, wcr[4 * i + 0], accC);                               \
        accC = fmaf(vv.y, wcr[4 * i + 1], accC);                               \
        accC = fmaf(vv.z, wcr[4 * i + 2], accC);                               \
        accC = fmaf(vv.w, wcr[4 * i + 3], accC);                               \
      }                                                                        \
      partHR[kg][j] = make_float2(accH, accR);                                 \
      partC[kg2][cc] = accC;                                                   \
    } else if (lt < 32) {                                                      \
      ((float4*)xring[(t_ + 2) & 7])[lt] = XQ_;                                \
      int rr = t_ + 6;                                                         \
      rr = rr > (NT - 1) ? (NT - 1) : rr;                                      \
      XQ_ = xr4[rr * 32 + lt];                                                 \
    }                                                                          \
    wg_barrier();                                                              \
    if (tid < NU) {                                                            \
      float2 p0 = partHR[0][j], p1 = partHR[1][j];                             \
      float2 p2 = partHR[2][j], p3 = partHR[3][j];                             \
      float hs = bias1 + p0.x + p1.x + p2.x + p3.x;                            \
      float rs = bias2 + p0.y + p1.y + p2.y + p3.y;                            \
      vst[j] = fast_tanh(hs) + fast_tanh(rs);                                  \
    } else if (tid >= 128 && tid < 192 && t_ >= 1) {                           \
      float cs = biasc;                                                        \
      _Pragma("unroll") for (int g = 0; g < 8; ++g) cs += partC[g][cc];        \
      out[((size_t)b * NT + (t_ - 1)) * NC + cc] = cs;                         \
    }                                                                          \
    wg_barrier();                                                              \
  }

  for (int t0 = 0; t0 < NT; t0 += 4) {
    STEP(t0 + 0, xq0)
    STEP(t0 + 1, xq1)
    STEP(t0 + 2, xq2)
    STEP(t0 + 3, xq3)
  }

  // tail: classifier for y_{T-1}
  if (tid < 512) {
    float accC = 0.f;
    const float4* vc4 = (const float4*)(&vst[kg2 * 16]);
#pragma unroll
    for (int i = 0; i < 4; ++i) {
      float4 vv = vc4[i];
      accC = fmaf(vv.x, wcr[4 * i + 0], accC);
      accC = fmaf(vv.y, wcr[4 * i + 1], accC);
      accC = fmaf(vv.z, wcr[4 * i + 2], accC);
      accC = fmaf(vv.w, wcr[4 * i + 3], accC);
    }
    partC[kg2][cc] = accC;
  }
  wg_barrier();
  if (tid >= 128 && tid < 192) {
    float cs = biasc;
#pragma unroll
    for (int g = 0; g < 8; ++g) cs += partC[g][cc];
    out[((size_t)b * NT + (NT - 1)) * NC + cc] = cs;
  }
}

extern "C" void kernel_launch(void* const* d_in, const int* in_sizes, int n_in,
                              void* d_out, int out_size, void* d_ws, size_t ws_size,
                              hipStream_t stream) {
  (void)in_sizes; (void)n_in; (void)d_ws; (void)ws_size; (void)out_size;
  const float* x   = (const float*)d_in[0];
  const float* W1  = (const float*)d_in[1];
  const float* b1v = (const float*)d_in[2];
  const float* W2  = (const float*)d_in[3];
  const float* b2v = (const float*)d_in[4];
  const float* Wc  = (const float*)d_in[5];
  const float* bcv = (const float*)d_in[6];
  float* out = (float*)d_out;

  hipLaunchKernelGGL(rnn_fused, dim3(NB), dim3(576), 0, stream,
                     x, W1, b1v, W2, b2v, Wc, bcv, out);
}

// Round 2
// 480.709 us; speedup vs baseline: 1.0591x; 1.0591x over previous
//
#include <hip/hip_runtime.h>

#define NB 256   // batch
#define NT 512   // time steps
#define ND 128   // input dim
#define NU 128   // hidden dim
#define NC 64    // classes

typedef float v2f __attribute__((ext_vector_type(2)));

// fast tanh: 1 - 2/(e^{2x}+1); exact limits for |x| large, ~1e-6 abs error
__device__ __forceinline__ float fast_tanh(float x) {
  float e = __expf(2.0f * x);
  return 1.0f - 2.0f / (e + 1.0f);
}

// LDS-only barrier: drain LDS ops then barrier (no vmem drain).
__device__ __forceinline__ void wg_barrier() {
  asm volatile("s_waitcnt lgkmcnt(0)\n\ts_barrier" ::: "memory");
}

// broadcast lane `i` of v to all lanes (readlane -> SGPR, free splat)
__device__ __forceinline__ float bcast(float v, int i) {
  return __builtin_bit_cast(float, __builtin_amdgcn_readlane(__builtin_bit_cast(int, v), i));
}

// Block: 256 threads = 4 waves. Wave kg owns k-slice [kg*32, kg*32+32).
// Lane l computes output columns j=l and j=l+64 (packed float2), classifier col c=l.
// One barrier per step; partials double-buffered on t&1.
__global__ __launch_bounds__(256, 1) void rnn_fused(
    const float* __restrict__ x,    // (B,T,D)
    const float* __restrict__ W1,   // (D,U)
    const float* __restrict__ b1v,  // (U)
    const float* __restrict__ W2,   // (U,U)
    const float* __restrict__ b2v,  // (U)
    const float* __restrict__ Wc,   // (U,C)
    const float* __restrict__ bcv,  // (C)
    float* __restrict__ out)        // (B,T,C)
{
  __shared__ float xring[16][ND];   // x-row ring, staged 8 ahead
  __shared__ float pH[2][4][NU];    // H partials per k-group, dbuf
  __shared__ float pR[2][4][NU];    // R partials
  __shared__ float pC[2][4][NC];    // classifier partials

  const int tid  = (int)threadIdx.x;
  const int lane = tid & 63;
  const int kg   = tid >> 6;        // wave id 0..3
  const int b    = (int)blockIdx.x;
  const float*  xrow = x + (size_t)b * NT * ND;
  const float4* xr4  = (const float4*)xrow;

  // --- weight fragments in registers ---
  v2f   w1f[32], w2f[32];
  float wcf[32];
#pragma unroll
  for (int i = 0; i < 32; ++i) {
    int k = kg * 32 + i;
    w1f[i] = (v2f){ W1[k * NU + lane], W1[k * NU + lane + 64] };
    w2f[i] = (v2f){ W2[k * NU + lane], W2[k * NU + lane + 64] };
    wcf[i] = Wc[k * NC + lane];
  }
  const float biasc = bcv[lane];
  float bias1 = 0.f, bias2 = 0.f;
  if (lane < 32) { bias1 = b1v[kg * 32 + lane]; bias2 = b2v[kg * 32 + lane]; }

  // --- staging prologue: rows 0..7 -> LDS; row kg+8 in reg ---
  float4 stg = make_float4(0.f, 0.f, 0.f, 0.f);
  if (lane < 32) {
    float4 a0 = xr4[(kg + 0) * 32 + lane];
    float4 a1 = xr4[(kg + 4) * 32 + lane];
    ((float4*)xring[kg + 0])[lane] = a0;
    ((float4*)xring[kg + 4])[lane] = a1;
    stg = xr4[(kg + 8) * 32 + lane];
  }
  float yseg = 0.f;   // lanes<32: y[kg*32+lane] of previous step (y_{-1}=0)
  wg_barrier();

  for (int t = 0; t < NT; ++t) {
    const int pb = t & 1;

    // ---- phase A: partials for step t ----
    // H: x_t @ W1 (independent of y -> scheduler can hide reduce latency of t-1)
    v2f accH0 = {0.f, 0.f}, accH1 = {0.f, 0.f};
    const float4* xb = (const float4*)&xring[t & 15][kg * 32];
#pragma unroll
    for (int i = 0; i < 4; ++i) {
      float4 xa = xb[2 * i];
      float4 xc = xb[2 * i + 1];
      accH0 = w1f[8*i+0] * (v2f){xa.x, xa.x} + accH0;
      accH1 = w1f[8*i+1] * (v2f){xa.y, xa.y} + accH1;
      accH0 = w1f[8*i+2] * (v2f){xa.z, xa.z} + accH0;
      accH1 = w1f[8*i+3] * (v2f){xa.w, xa.w} + accH1;
      accH0 = w1f[8*i+4] * (v2f){xc.x, xc.x} + accH0;
      accH1 = w1f[8*i+5] * (v2f){xc.y, xc.y} + accH1;
      accH0 = w1f[8*i+6] * (v2f){xc.z, xc.z} + accH0;
      accH1 = w1f[8*i+7] * (v2f){xc.w, xc.w} + accH1;
    }
    v2f accH = accH0 + accH1;

    // R: y_{t-1} @ W2, C: y_{t-1} @ Wc — scalars via readlane of own segment
    v2f accR0 = {0.f, 0.f}, accR1 = {0.f, 0.f};
    float accC0 = 0.f, accC1 = 0.f;
#pragma unroll
    for (int i = 0; i < 16; ++i) {
      float s0 = bcast(yseg, 2 * i);
      float s1 = bcast(yseg, 2 * i + 1);
      accR0 = w2f[2*i+0] * (v2f){s0, s0} + accR0;
      accR1 = w2f[2*i+1] * (v2f){s1, s1} + accR1;
      accC0 = fmaf(s0, wcf[2*i+0], accC0);
      accC1 = fmaf(s1, wcf[2*i+1], accC1);
    }
    v2f accR = accR0 + accR1;
    float accC = accC0 + accC1;

    // ---- phase B: write partials (dbuf pb) ----
    pH[pb][kg][lane]      = accH.x;
    pH[pb][kg][lane + 64] = accH.y;
    pR[pb][kg][lane]      = accR.x;
    pR[pb][kg][lane + 64] = accR.y;
    pC[pb][kg][lane]      = accC;

    // ---- staging: wave t&3 writes row t+8 (loaded 4 iters ago), loads t+12 ----
    if (kg == (t & 3)) {
      if (lane < 32) {
        ((float4*)xring[(t + 8) & 15])[lane] = stg;
        int r = t + 12; r = (r < NT) ? r : (NT - 1);
        stg = xr4[r * 32 + lane];
      }
    }

    wg_barrier();

    // ---- phase D: reduce own segment -> y_t (lanes 0..31) ----
    if (lane < 32) {
      const int j = kg * 32 + lane;
      float hs = bias1, rs = bias2;
#pragma unroll
      for (int g = 0; g < 4; ++g) { hs += pH[pb][g][j]; rs += pR[pb][g][j]; }
      yseg = fast_tanh(hs) + fast_tanh(rs);
    }

    // classifier output for y_{t-1} by wave (t+2)&3 (never the staging wave)
    if (kg == ((t + 2) & 3) && t >= 1) {
      float cs = biasc;
#pragma unroll
      for (int g = 0; g < 4; ++g) cs += pC[pb][g][lane];
      out[((size_t)b * NT + (t - 1)) * NC + lane] = cs;
    }
    // no trailing barrier: next step writes buffer pb^1; xring slots 8 apart
  }

  // ---- epilogue: classifier for y_{NT-1} ----
  float accC0 = 0.f, accC1 = 0.f;
#pragma unroll
  for (int i = 0; i < 16; ++i) {
    float s0 = bcast(yseg, 2 * i);
    float s1 = bcast(yseg, 2 * i + 1);
    accC0 = fmaf(s0, wcf[2*i+0], accC0);
    accC1 = fmaf(s1, wcf[2*i+1], accC1);
  }
  pC[0][kg][lane] = accC0 + accC1;
  wg_barrier();
  if (kg == 0) {
    float cs = biasc;
#pragma unroll
    for (int g = 0; g < 4; ++g) cs += pC[0][g][lane];
    out[((size_t)b * NT + (NT - 1)) * NC + lane] = cs;
  }
}

extern "C" void kernel_launch(void* const* d_in, const int* in_sizes, int n_in,
                              void* d_out, int out_size, void* d_ws, size_t ws_size,
                              hipStream_t stream) {
  (void)in_sizes; (void)n_in; (void)d_ws; (void)ws_size; (void)out_size;
  const float* x   = (const float*)d_in[0];
  const float* W1  = (const float*)d_in[1];
  const float* b1v = (const float*)d_in[2];
  const float* W2  = (const float*)d_in[3];
  const float* b2v = (const float*)d_in[4];
  const float* Wc  = (const float*)d_in[5];
  const float* bcv = (const float*)d_in[6];
  float* out = (float*)d_out;

  hipLaunchKernelGGL(rnn_fused, dim3(NB), dim3(256), 0, stream,
                     x, W1, b1v, W2, b2v, Wc, bcv, out);
}